// Round 2
// baseline (476.121 us; speedup 1.0000x reference)
//
#include <hip/hip_runtime.h>
#include <hip/hip_bf16.h>

// Problem constants
#define NB 2
#define NT 2048
#define NC 1024          // C
#define NE 8             // experts
#define NH 2048          // H
#define NN (NB*NT)       // 4096 tokens
#define NSLOT (NN*2)     // 8192 routed (token,expert) slots

typedef short s16x8 __attribute__((ext_vector_type(8)));   // 8 bf16 (4 VGPRs)
typedef float f32x4 __attribute__((ext_vector_type(4)));

__device__ __forceinline__ unsigned short f2bf(float f) {
  union { float f; unsigned int u; } v; v.f = f;
  unsigned int r = v.u + 0x7FFFu + ((v.u >> 16) & 1u);  // RNE
  return (unsigned short)(r >> 16);
}

// async global->LDS, 16B/lane. LDS dest is wave-uniform base + lane*16.
#define GLOAD_LDS16(gp, lp) \
  __builtin_amdgcn_global_load_lds( \
      (const __attribute__((address_space(1))) void*)(gp), \
      (__attribute__((address_space(3))) void*)(lp), 16, 0, 0)

// ---------------- f32 -> bf16 elementwise (x) ----------------
__global__ void cvt_kernel(const float* __restrict__ in,
                           unsigned short* __restrict__ out, int n4) {
  int i = blockIdx.x * blockDim.x + threadIdx.x;
  if (i >= n4) return;
  float4 v = ((const float4*)in)[i];
  ushort4 o;
  o.x = f2bf(v.x); o.y = f2bf(v.y); o.z = f2bf(v.z); o.w = f2bf(v.w);
  ((ushort4*)out)[i] = o;
}

// -------- per-expert transpose + f32->bf16: in [R][Cc] -> out [Cc][R] --------
__global__ void tcvt_kernel(const float* __restrict__ in,
                            unsigned short* __restrict__ out, int R, int Cc) {
  __shared__ unsigned short tile[32][33];
  const size_t eb = (size_t)blockIdx.z * R * Cc;
  const float* ip = in + eb;
  unsigned short* op = out + eb;
  int c0 = blockIdx.x * 32, r0 = blockIdx.y * 32;
  int tx = threadIdx.x, ty = threadIdx.y;
  #pragma unroll
  for (int j = ty; j < 32; j += 8)
    tile[j][tx] = f2bf(ip[(size_t)(r0 + j) * Cc + c0 + tx]);
  __syncthreads();
  #pragma unroll
  for (int j = ty; j < 32; j += 8)
    op[(size_t)(c0 + j) * R + r0 + tx] = tile[tx][j];
}

// ---------------- router: scores = x@Wg, top-2, softmax ----------------
__global__ void router_kernel(const float* __restrict__ x, const float* __restrict__ Wg,
                              int* __restrict__ tk_idx, float* __restrict__ tk_p,
                              int* __restrict__ counts) {
  int lane = threadIdx.x & 63;
  int n = blockIdx.x * 4 + (threadIdx.x >> 6);   // 4 waves/block, 1 token/wave
  const float* xr = x + (size_t)n * NC;
  float sc[NE];
  #pragma unroll
  for (int e = 0; e < NE; ++e) sc[e] = 0.f;
  for (int i = 0; i < NC / 64; ++i) {
    int c = i * 64 + lane;
    float xv = xr[c];
    const float4* wr = (const float4*)(Wg + (size_t)c * NE);
    float4 w0 = wr[0], w1 = wr[1];
    sc[0] += xv * w0.x; sc[1] += xv * w0.y; sc[2] += xv * w0.z; sc[3] += xv * w0.w;
    sc[4] += xv * w1.x; sc[5] += xv * w1.y; sc[6] += xv * w1.z; sc[7] += xv * w1.w;
  }
  #pragma unroll
  for (int e = 0; e < NE; ++e) {
    float v = sc[e];
    for (int s = 32; s >= 1; s >>= 1) v += __shfl_xor(v, s);
    sc[e] = v;
  }
  if (lane == 0) {
    int i0 = 0;
    #pragma unroll
    for (int e = 1; e < NE; ++e) if (sc[e] > sc[i0]) i0 = e;   // first-on-tie like lax.top_k
    int i1 = (i0 == 0) ? 1 : 0;
    #pragma unroll
    for (int e = 0; e < NE; ++e) if (e != i0 && sc[e] > sc[i1]) i1 = e;
    float e1 = __expf(sc[i1] - sc[i0]);
    float inv = 1.f / (1.f + e1);
    tk_idx[n * 2] = i0; tk_idx[n * 2 + 1] = i1;
    tk_p[n * 2] = inv;  tk_p[n * 2 + 1] = e1 * inv;
    atomicAdd(&counts[i0], 1); atomicAdd(&counts[i1], 1);
  }
}

// ---------------- tiny prefix sum over 8 expert counts ----------------
__global__ void scan_kernel(const int* __restrict__ counts, int* __restrict__ offs,
                            int* __restrict__ cursor) {
  if (threadIdx.x == 0) {
    int a = 0;
    for (int e = 0; e < NE; ++e) { offs[e] = a; a += counts[e]; }
    offs[NE] = a;   // == NSLOT
  }
  if (threadIdx.x < NE) cursor[threadIdx.x] = 0;
}

// ---------------- scatter tokens into per-expert buckets ----------------
__global__ void scatter_kernel(const int* __restrict__ tk_idx, const float* __restrict__ tk_p,
                               const int* __restrict__ offs, int* __restrict__ cursor,
                               int* __restrict__ slot_token, float* __restrict__ slot_w,
                               int* __restrict__ slot_of) {
  int n = blockIdx.x * blockDim.x + threadIdx.x;
  if (n >= NN) return;
  #pragma unroll
  for (int k = 0; k < 2; ++k) {
    int e = tk_idx[n * 2 + k];
    int pos = offs[e] + atomicAdd(&cursor[e], 1);
    slot_token[pos] = n;
    slot_w[pos] = tk_p[n * 2 + k];
    slot_of[n * 2 + k] = pos;
  }
}

// ---------------- grouped GEMM, m97 structure ----------------
// A [*][K] bf16 (rows gathered via slot_token if GATHER else direct slot rows)
// Bt [NE][Nn][K] bf16 (k-contiguous = pre-transposed weight)
// SILU=1: Out bf16 [NSLOT][Nn] = silu(A@B);  SILU=0: Out f32 = slot_w * (A@B)
template <int SILU, int GATHER>
__global__ __launch_bounds__(256, 2) void moe_gemm_kernel(
    const unsigned short* __restrict__ A, const unsigned short* __restrict__ Bt,
    void* __restrict__ Out, const int* __restrict__ slot_token,
    const float* __restrict__ slot_w, const int* __restrict__ offs, int K, int Nn) {
  __shared__ unsigned short lds_a[128 * 32];
  __shared__ unsigned short lds_b[128 * 32];
  const int e = blockIdx.z;
  const int off = offs[e];
  const int me = offs[e + 1] - off;
  const int rbase = blockIdx.y * 128;
  if (rbase >= me) return;                  // early-exit beyond this expert's rows
  const int n0 = blockIdx.x * 128;
  const int tid = threadIdx.x, lane = tid & 63, w = tid >> 6;
  const int wm = w >> 1, wn = w & 1;        // 2x2 wave grid, 64x64 out per wave

  // staging: wave w covers tile rows [w*32, w*32+32), 2 issues of 16 rows
  const int sr = w * 32 + (lane >> 2);
  const int scb = (lane & 3) * 16;          // byte offset within a 32-elem k-row
  const int gr0 = rbase + sr, gr1 = gr0 + 16;
  int ar0, ar1;
  if (GATHER) {
    ar0 = (gr0 < me) ? slot_token[off + gr0] : 0;
    ar1 = (gr1 < me) ? slot_token[off + gr1] : 0;
  } else {
    ar0 = (gr0 < me) ? (off + gr0) : 0;
    ar1 = (gr1 < me) ? (off + gr1) : 0;
  }
  const char* srcA0 = (const char*)(A + (size_t)ar0 * K) + scb;
  const char* srcA1 = (const char*)(A + (size_t)ar1 * K) + scb;
  const char* srcB0 = (const char*)(Bt + ((size_t)e * Nn + n0 + sr) * K) + scb;
  const char* srcB1 = (const char*)(Bt + ((size_t)e * Nn + n0 + sr + 16) * K) + scb;
  char* la = (char*)lds_a;
  char* lb = (char*)lds_b;
  char* dstA0 = la + w * 2048;              // wave-uniform LDS bases
  char* dstA1 = la + w * 2048 + 1024;
  char* dstB0 = lb + w * 2048;
  char* dstB1 = lb + w * 2048 + 1024;

  f32x4 zero = {0.f, 0.f, 0.f, 0.f};
  f32x4 acc[4][4];
  #pragma unroll
  for (int m = 0; m < 4; ++m)
    #pragma unroll
    for (int n = 0; n < 4; ++n) acc[m][n] = zero;

  // fragment read bases (LDS row stride = 32 bf16 = 64 B)
  const int arb = (wm * 64 + (lane & 15)) * 64 + (lane >> 4) * 16;
  const int brb = (wn * 64 + (lane & 15)) * 64 + (lane >> 4) * 16;

  for (int k0 = 0; k0 < K; k0 += 32) {
    const int kb = k0 * 2;
    GLOAD_LDS16(srcA0 + kb, dstA0);
    GLOAD_LDS16(srcA1 + kb, dstA1);
    GLOAD_LDS16(srcB0 + kb, dstB0);
    GLOAD_LDS16(srcB1 + kb, dstB1);
    __syncthreads();
    s16x8 a[4], b[4];
    #pragma unroll
    for (int m = 0; m < 4; ++m) a[m] = *(const s16x8*)(la + arb + m * 1024);
    #pragma unroll
    for (int n = 0; n < 4; ++n) b[n] = *(const s16x8*)(lb + brb + n * 1024);
    #pragma unroll
    for (int m = 0; m < 4; ++m)
      #pragma unroll
      for (int n = 0; n < 4; ++n)
        acc[m][n] = __builtin_amdgcn_mfma_f32_16x16x32_bf16(a[m], b[n], acc[m][n], 0, 0, 0);
    __syncthreads();
  }

  // epilogue: D row=(lane>>4)*4+r, col=lane&15 (measured layout)
  if (SILU) {
    unsigned short* O = (unsigned short*)Out;
    #pragma unroll
    for (int m = 0; m < 4; ++m)
      #pragma unroll
      for (int r = 0; r < 4; ++r) {
        int row = wm * 64 + m * 16 + ((lane >> 4) << 2) + r;
        if (rbase + row < me) {
          size_t base = (size_t)(off + rbase + row) * Nn + n0 + wn * 64 + (lane & 15);
          #pragma unroll
          for (int n = 0; n < 4; ++n) {
            float v = acc[m][n][r];
            O[base + n * 16] = f2bf(v / (1.f + __expf(-v)));   // silu
          }
        }
      }
  } else {
    float* O = (float*)Out;
    #pragma unroll
    for (int m = 0; m < 4; ++m)
      #pragma unroll
      for (int r = 0; r < 4; ++r) {
        int row = wm * 64 + m * 16 + ((lane >> 4) << 2) + r;
        if (rbase + row < me) {
          float p = slot_w[off + rbase + row];
          size_t base = (size_t)(off + rbase + row) * Nn + n0 + wn * 64 + (lane & 15);
          #pragma unroll
          for (int n = 0; n < 4; ++n) O[base + n * 16] = p * acc[m][n][r];
        }
      }
  }
}

// ---------------- combine the 2 expert outputs per token ----------------
__global__ void combine_kernel(const float* __restrict__ Eo, const int* __restrict__ slot_of,
                               float* __restrict__ y) {
  int n = blockIdx.x;
  int t = threadIdx.x;
  int s0 = slot_of[n * 2], s1 = slot_of[n * 2 + 1];
  float4 va = ((const float4*)(Eo + (size_t)s0 * NC))[t];
  float4 vb = ((const float4*)(Eo + (size_t)s1 * NC))[t];
  float4 o;
  o.x = va.x + vb.x; o.y = va.y + vb.y; o.z = va.z + vb.z; o.w = va.w + vb.w;
  ((float4*)(y + (size_t)n * NC))[t] = o;
}

extern "C" void kernel_launch(void* const* d_in, const int* in_sizes, int n_in,
                              void* d_out, int out_size, void* d_ws, size_t ws_size,
                              hipStream_t stream) {
  const float* x  = (const float*)d_in[0];
  const float* Wg = (const float*)d_in[1];
  const float* W1 = (const float*)d_in[2];
  const float* W2 = (const float*)d_in[3];
  float* y = (float*)d_out;

  char* p = (char*)d_ws;
  auto carve = [&](size_t bytes) {
    char* r = p;
    p += (bytes + 255) & ~(size_t)255;
    return r;
  };
  unsigned short* xbf  = (unsigned short*)carve((size_t)NN * NC * 2);     // 8.4 MB
  unsigned short* w1t  = (unsigned short*)carve((size_t)NE * NH * NC * 2); // 33.6 MB [E][H][C]
  unsigned short* w2t  = (unsigned short*)carve((size_t)NE * NC * NH * 2); // 33.6 MB [E][C][H]
  unsigned short* hbuf = (unsigned short*)carve((size_t)NSLOT * NH * 2);   // 33.6 MB
  float* eo = (float*)w1t;  // alias: W1t dead after gemm1; Eo written in gemm2 (same 33.6 MB)
  int*   tk_idx     = (int*)carve(NSLOT * 4);
  float* tk_p       = (float*)carve(NSLOT * 4);
  int*   slot_token = (int*)carve(NSLOT * 4);
  float* slot_w     = (float*)carve(NSLOT * 4);
  int*   slot_of    = (int*)carve(NSLOT * 4);
  int*   counts     = (int*)carve(NE * 4);
  int*   offs       = (int*)carve((NE + 1) * 4);
  int*   cursor     = (int*)carve(NE * 4);

  hipMemsetAsync(counts, 0, NE * 4, stream);

  // dtype/layout conversions
  cvt_kernel<<<dim3(NN * NC / 4 / 256), 256, 0, stream>>>(x, xbf, NN * NC / 4);
  tcvt_kernel<<<dim3(NH / 32, NC / 32, NE), dim3(32, 8), 0, stream>>>(W1, w1t, NC, NH);
  tcvt_kernel<<<dim3(NC / 32, NH / 32, NE), dim3(32, 8), 0, stream>>>(W2, w2t, NH, NC);

  // routing
  router_kernel<<<dim3(NN / 4), 256, 0, stream>>>(x, Wg, tk_idx, tk_p, counts);
  scan_kernel<<<1, 64, 0, stream>>>(counts, offs, cursor);
  scatter_kernel<<<dim3((NN + 255) / 256), 256, 0, stream>>>(tk_idx, tk_p, offs, cursor,
                                                             slot_token, slot_w, slot_of);

  // expert GEMMs (grouped, early-exit tiles beyond each expert's row count)
  moe_gemm_kernel<1, 1><<<dim3(NH / 128, NN / 128, NE), 256, 0, stream>>>(
      xbf, w1t, hbuf, slot_token, slot_w, offs, NC, NH);
  moe_gemm_kernel<0, 0><<<dim3(NC / 128, NN / 128, NE), 256, 0, stream>>>(
      hbuf, w2t, eo, slot_token, slot_w, offs, NH, NC);

  // weighted combine of each token's 2 expert rows
  combine_kernel<<<dim3(NN), 256, 0, stream>>>(eo, slot_of, y);
}

// Round 4
// 379.079 us; speedup vs baseline: 1.2560x; 1.2560x over previous
//
#include <hip/hip_runtime.h>
#include <hip/hip_bf16.h>

// Problem constants
#define NB 2
#define NT 2048
#define NC 1024          // C
#define NE 8             // experts
#define NH 2048          // H
#define NN (NB*NT)       // 4096 tokens
#define NSLOT (NN*2)     // 8192 routed (token,expert) slots

typedef short s16x8 __attribute__((ext_vector_type(8)));   // 8 bf16 (4 VGPRs)
typedef float f32x4 __attribute__((ext_vector_type(4)));

__device__ __forceinline__ unsigned short f2bf(float f) {
  union { float f; unsigned int u; } v; v.f = f;
  unsigned int r = v.u + 0x7FFFu + ((v.u >> 16) & 1u);  // RNE
  return (unsigned short)(r >> 16);
}

// async global->LDS, 16B/lane. LDS dest is wave-uniform base + lane*16.
#define GLOAD_LDS16(gp, lp) \
  __builtin_amdgcn_global_load_lds( \
      (const __attribute__((address_space(1))) void*)(gp), \
      (__attribute__((address_space(3))) void*)(lp), 16, 0, 0)

// ---------------- f32 -> bf16 elementwise (x) ----------------
__global__ void cvt_kernel(const float* __restrict__ in,
                           unsigned short* __restrict__ out, int n4) {
  int i = blockIdx.x * blockDim.x + threadIdx.x;
  if (i >= n4) return;
  float4 v = ((const float4*)in)[i];
  ushort4 o;
  o.x = f2bf(v.x); o.y = f2bf(v.y); o.z = f2bf(v.z); o.w = f2bf(v.w);
  ((ushort4*)out)[i] = o;
}

// -------- per-expert transpose + f32->bf16: in [R][Cc] -> out [Cc][R] --------
__global__ void tcvt_kernel(const float* __restrict__ in,
                            unsigned short* __restrict__ out, int R, int Cc) {
  __shared__ unsigned short tile[32][33];
  const size_t eb = (size_t)blockIdx.z * R * Cc;
  const float* ip = in + eb;
  unsigned short* op = out + eb;
  int c0 = blockIdx.x * 32, r0 = blockIdx.y * 32;
  int tx = threadIdx.x, ty = threadIdx.y;
  #pragma unroll
  for (int j = ty; j < 32; j += 8)
    tile[j][tx] = f2bf(ip[(size_t)(r0 + j) * Cc + c0 + tx]);
  __syncthreads();
  #pragma unroll
  for (int j = ty; j < 32; j += 8)
    op[(size_t)(c0 + j) * R + r0 + tx] = tile[tx][j];
}

// ---------------- router: scores = x@Wg, top-2, softmax (NO atomics) --------
__global__ void router_kernel(const float* __restrict__ x, const float* __restrict__ Wg,
                              int* __restrict__ tk_idx, float* __restrict__ tk_p) {
  int lane = threadIdx.x & 63;
  int n = blockIdx.x * 4 + (threadIdx.x >> 6);   // 4 waves/block, 1 token/wave
  const float4* xr = (const float4*)(x + (size_t)n * NC);
  float sc[NE];
  #pragma unroll
  for (int e = 0; e < NE; ++e) sc[e] = 0.f;
  #pragma unroll
  for (int i = 0; i < NC / 4 / 64; ++i) {        // 4 iters of float4
    int c4 = i * 64 + lane;                       // float4 index; c = c4*4
    float4 xv = xr[c4];
    const float4* wr = (const float4*)(Wg + (size_t)c4 * 4 * NE);
    #pragma unroll
    for (int j = 0; j < 4; ++j) {
      float xj = (j == 0) ? xv.x : (j == 1) ? xv.y : (j == 2) ? xv.z : xv.w;
      float4 w0 = wr[j * 2], w1 = wr[j * 2 + 1];
      sc[0] += xj * w0.x; sc[1] += xj * w0.y; sc[2] += xj * w0.z; sc[3] += xj * w0.w;
      sc[4] += xj * w1.x; sc[5] += xj * w1.y; sc[6] += xj * w1.z; sc[7] += xj * w1.w;
    }
  }
  #pragma unroll
  for (int e = 0; e < NE; ++e) {
    float v = sc[e];
    for (int s = 32; s >= 1; s >>= 1) v += __shfl_xor(v, s);
    sc[e] = v;
  }
  if (lane == 0) {
    int i0 = 0;
    #pragma unroll
    for (int e = 1; e < NE; ++e) if (sc[e] > sc[i0]) i0 = e;   // first-on-tie like lax.top_k
    int i1 = (i0 == 0) ? 1 : 0;
    #pragma unroll
    for (int e = 0; e < NE; ++e) if (e != i0 && sc[e] > sc[i1]) i1 = e;
    float e1 = __expf(sc[i1] - sc[i0]);
    float inv = 1.f / (1.f + e1);
    tk_idx[n * 2] = i0; tk_idx[n * 2 + 1] = i1;
    tk_p[n * 2] = inv;  tk_p[n * 2 + 1] = e1 * inv;
  }
}

// ------- single-block scan+scatter: ballot histogram, zero atomics ----------
// 256 threads = 4 waves; each wave owns 32 chunks of 64 entries (NSLOT=8192).
__global__ void route_scan_scatter(const int* __restrict__ tk_idx,
                                   const float* __restrict__ tk_p,
                                   int* __restrict__ offs,
                                   int* __restrict__ slot_token,
                                   float* __restrict__ slot_w,
                                   int* __restrict__ slot_of) {
  __shared__ int wcnt[4][NE];
  __shared__ int basel[4][NE];
  const int lane = threadIdx.x & 63, w = threadIdx.x >> 6;
  const unsigned long long lt = (1ull << lane) - 1ull;

  // phase 1: per-wave expert histogram via ballots
  int cnt0 = 0, cnt1 = 0, cnt2 = 0, cnt3 = 0, cnt4 = 0, cnt5 = 0, cnt6 = 0, cnt7 = 0;
  for (int ch = 0; ch < 32; ++ch) {
    int entry = (w * 32 + ch) * 64 + lane;
    int em = tk_idx[entry];
    cnt0 += __popcll(__ballot(em == 0));
    cnt1 += __popcll(__ballot(em == 1));
    cnt2 += __popcll(__ballot(em == 2));
    cnt3 += __popcll(__ballot(em == 3));
    cnt4 += __popcll(__ballot(em == 4));
    cnt5 += __popcll(__ballot(em == 5));
    cnt6 += __popcll(__ballot(em == 6));
    cnt7 += __popcll(__ballot(em == 7));
  }
  if (lane < NE) {
    int v = 0;
    if (lane == 0) v = cnt0; if (lane == 1) v = cnt1;
    if (lane == 2) v = cnt2; if (lane == 3) v = cnt3;
    if (lane == 4) v = cnt4; if (lane == 5) v = cnt5;
    if (lane == 6) v = cnt6; if (lane == 7) v = cnt7;
    wcnt[w][lane] = v;
  }
  __syncthreads();

  // phase 2: serial scan over 4x8 (thread 0)
  if (threadIdx.x == 0) {
    int a = 0;
    for (int e = 0; e < NE; ++e) {
      offs[e] = a;
      int s = a;
      for (int w2 = 0; w2 < 4; ++w2) { basel[w2][e] = s; s += wcnt[w2][e]; }
      a = s;
    }
    offs[NE] = a;   // == NSLOT
  }
  __syncthreads();

  // phase 3: assign positions (stable within wave; order is irrelevant anyway)
  int rb0 = basel[w][0], rb1 = basel[w][1], rb2 = basel[w][2], rb3 = basel[w][3];
  int rb4 = basel[w][4], rb5 = basel[w][5], rb6 = basel[w][6], rb7 = basel[w][7];
  for (int ch = 0; ch < 32; ++ch) {
    int entry = (w * 32 + ch) * 64 + lane;
    int em = tk_idx[entry];
    int pos = 0;
    unsigned long long m;
    m = __ballot(em == 0); if (em == 0) pos = rb0 + __popcll(m & lt); rb0 += __popcll(m);
    m = __ballot(em == 1); if (em == 1) pos = rb1 + __popcll(m & lt); rb1 += __popcll(m);
    m = __ballot(em == 2); if (em == 2) pos = rb2 + __popcll(m & lt); rb2 += __popcll(m);
    m = __ballot(em == 3); if (em == 3) pos = rb3 + __popcll(m & lt); rb3 += __popcll(m);
    m = __ballot(em == 4); if (em == 4) pos = rb4 + __popcll(m & lt); rb4 += __popcll(m);
    m = __ballot(em == 5); if (em == 5) pos = rb5 + __popcll(m & lt); rb5 += __popcll(m);
    m = __ballot(em == 6); if (em == 6) pos = rb6 + __popcll(m & lt); rb6 += __popcll(m);
    m = __ballot(em == 7); if (em == 7) pos = rb7 + __popcll(m & lt); rb7 += __popcll(m);
    slot_token[pos] = entry >> 1;
    slot_w[pos] = tk_p[entry];
    slot_of[entry] = pos;
  }
}

// ---------------- grouped GEMM, m97 structure ----------------
// A [*][K] bf16 (rows gathered via slot_token if GATHER else direct slot rows)
// Bt [NE][Nn][K] bf16 (k-contiguous = pre-transposed weight)
// SILU=1: Out bf16 [NSLOT][Nn] = silu(A@B);  SILU=0: Out f32 = slot_w * (A@B)
template <int SILU, int GATHER>
__global__ __launch_bounds__(256, 2) void moe_gemm_kernel(
    const unsigned short* __restrict__ A, const unsigned short* __restrict__ Bt,
    void* __restrict__ Out, const int* __restrict__ slot_token,
    const float* __restrict__ slot_w, const int* __restrict__ offs, int K, int Nn) {
  __shared__ unsigned short lds_a[128 * 32];
  __shared__ unsigned short lds_b[128 * 32];
  const int e = blockIdx.z;
  const int off = offs[e];
  const int me = offs[e + 1] - off;
  const int rbase = blockIdx.y * 128;
  if (rbase >= me) return;                  // early-exit beyond this expert's rows
  const int n0 = blockIdx.x * 128;
  const int tid = threadIdx.x, lane = tid & 63, w = tid >> 6;
  const int wm = w >> 1, wn = w & 1;        // 2x2 wave grid, 64x64 out per wave

  // staging: wave w covers tile rows [w*32, w*32+32), 2 issues of 16 rows
  const int sr = w * 32 + (lane >> 2);
  const int scb = (lane & 3) * 16;          // byte offset within a 32-elem k-row
  const int gr0 = rbase + sr, gr1 = gr0 + 16;
  int ar0, ar1;
  if (GATHER) {
    ar0 = (gr0 < me) ? slot_token[off + gr0] : 0;
    ar1 = (gr1 < me) ? slot_token[off + gr1] : 0;
  } else {
    ar0 = (gr0 < me) ? (off + gr0) : 0;
    ar1 = (gr1 < me) ? (off + gr1) : 0;
  }
  const char* srcA0 = (const char*)(A + (size_t)ar0 * K) + scb;
  const char* srcA1 = (const char*)(A + (size_t)ar1 * K) + scb;
  const char* srcB0 = (const char*)(Bt + ((size_t)e * Nn + n0 + sr) * K) + scb;
  const char* srcB1 = (const char*)(Bt + ((size_t)e * Nn + n0 + sr + 16) * K) + scb;
  char* la = (char*)lds_a;
  char* lb = (char*)lds_b;
  char* dstA0 = la + w * 2048;              // wave-uniform LDS bases
  char* dstA1 = la + w * 2048 + 1024;
  char* dstB0 = lb + w * 2048;
  char* dstB1 = lb + w * 2048 + 1024;

  f32x4 zero = {0.f, 0.f, 0.f, 0.f};
  f32x4 acc[4][4];
  #pragma unroll
  for (int m = 0; m < 4; ++m)
    #pragma unroll
    for (int n = 0; n < 4; ++n) acc[m][n] = zero;

  // fragment read bases (LDS row stride = 32 bf16 = 64 B)
  const int arb = (wm * 64 + (lane & 15)) * 64 + (lane >> 4) * 16;
  const int brb = (wn * 64 + (lane & 15)) * 64 + (lane >> 4) * 16;

  for (int k0 = 0; k0 < K; k0 += 32) {
    const int kb = k0 * 2;
    GLOAD_LDS16(srcA0 + kb, dstA0);
    GLOAD_LDS16(srcA1 + kb, dstA1);
    GLOAD_LDS16(srcB0 + kb, dstB0);
    GLOAD_LDS16(srcB1 + kb, dstB1);
    __syncthreads();
    s16x8 a[4], b[4];
    #pragma unroll
    for (int m = 0; m < 4; ++m) a[m] = *(const s16x8*)(la + arb + m * 1024);
    #pragma unroll
    for (int n = 0; n < 4; ++n) b[n] = *(const s16x8*)(lb + brb + n * 1024);
    #pragma unroll
    for (int m = 0; m < 4; ++m)
      #pragma unroll
      for (int n = 0; n < 4; ++n)
        acc[m][n] = __builtin_amdgcn_mfma_f32_16x16x32_bf16(a[m], b[n], acc[m][n], 0, 0, 0);
    __syncthreads();
  }

  // epilogue: D row=(lane>>4)*4+r, col=lane&15 (measured layout)
  if (SILU) {
    unsigned short* O = (unsigned short*)Out;
    #pragma unroll
    for (int m = 0; m < 4; ++m)
      #pragma unroll
      for (int r = 0; r < 4; ++r) {
        int row = wm * 64 + m * 16 + ((lane >> 4) << 2) + r;
        if (rbase + row < me) {
          size_t base = (size_t)(off + rbase + row) * Nn + n0 + wn * 64 + (lane & 15);
          #pragma unroll
          for (int n = 0; n < 4; ++n) {
            float v = acc[m][n][r];
            O[base + n * 16] = f2bf(v / (1.f + __expf(-v)));   // silu
          }
        }
      }
  } else {
    float* O = (float*)Out;
    #pragma unroll
    for (int m = 0; m < 4; ++m)
      #pragma unroll
      for (int r = 0; r < 4; ++r) {
        int row = wm * 64 + m * 16 + ((lane >> 4) << 2) + r;
        if (rbase + row < me) {
          float p = slot_w[off + rbase + row];
          size_t base = (size_t)(off + rbase + row) * Nn + n0 + wn * 64 + (lane & 15);
          #pragma unroll
          for (int n = 0; n < 4; ++n) O[base + n * 16] = p * acc[m][n][r];
        }
      }
  }
}

// ---------------- combine the 2 expert outputs per token ----------------
__global__ void combine_kernel(const float* __restrict__ Eo, const int* __restrict__ slot_of,
                               float* __restrict__ y) {
  int n = blockIdx.x;
  int t = threadIdx.x;
  int s0 = slot_of[n * 2], s1 = slot_of[n * 2 + 1];
  float4 va = ((const float4*)(Eo + (size_t)s0 * NC))[t];
  float4 vb = ((const float4*)(Eo + (size_t)s1 * NC))[t];
  float4 o;
  o.x = va.x + vb.x; o.y = va.y + vb.y; o.z = va.z + vb.z; o.w = va.w + vb.w;
  ((float4*)(y + (size_t)n * NC))[t] = o;
}

extern "C" void kernel_launch(void* const* d_in, const int* in_sizes, int n_in,
                              void* d_out, int out_size, void* d_ws, size_t ws_size,
                              hipStream_t stream) {
  const float* x  = (const float*)d_in[0];
  const float* Wg = (const float*)d_in[1];
  const float* W1 = (const float*)d_in[2];
  const float* W2 = (const float*)d_in[3];
  float* y = (float*)d_out;

  char* p = (char*)d_ws;
  auto carve = [&](size_t bytes) {
    char* r = p;
    p += (bytes + 255) & ~(size_t)255;
    return r;
  };
  unsigned short* xbf  = (unsigned short*)carve((size_t)NN * NC * 2);     // 8.4 MB
  unsigned short* w1t  = (unsigned short*)carve((size_t)NE * NH * NC * 2); // 33.6 MB [E][H][C]
  unsigned short* w2t  = (unsigned short*)carve((size_t)NE * NC * NH * 2); // 33.6 MB [E][C][H]
  unsigned short* hbuf = (unsigned short*)carve((size_t)NSLOT * NH * 2);   // 33.6 MB
  float* eo = (float*)w1t;  // alias: W1t dead after gemm1; Eo written in gemm2 (same 33.6 MB)
  int*   tk_idx     = (int*)carve(NSLOT * 4);
  float* tk_p       = (float*)carve(NSLOT * 4);
  int*   slot_token = (int*)carve(NSLOT * 4);
  float* slot_w     = (float*)carve(NSLOT * 4);
  int*   slot_of    = (int*)carve(NSLOT * 4);
  int*   offs       = (int*)carve((NE + 1) * 4);

  // dtype/layout conversions
  cvt_kernel<<<dim3(NN * NC / 4 / 256), 256, 0, stream>>>(x, xbf, NN * NC / 4);
  tcvt_kernel<<<dim3(NH / 32, NC / 32, NE), dim3(32, 8), 0, stream>>>(W1, w1t, NC, NH);
  tcvt_kernel<<<dim3(NC / 32, NH / 32, NE), dim3(32, 8), 0, stream>>>(W2, w2t, NH, NC);

  // routing (atomic-free)
  router_kernel<<<dim3(NN / 4), 256, 0, stream>>>(x, Wg, tk_idx, tk_p);
  route_scan_scatter<<<1, 256, 0, stream>>>(tk_idx, tk_p, offs,
                                            slot_token, slot_w, slot_of);

  // expert GEMMs (grouped, early-exit tiles beyond each expert's row count)
  moe_gemm_kernel<1, 1><<<dim3(NH / 128, NN / 128, NE), 256, 0, stream>>>(
      xbf, w1t, hbuf, slot_token, slot_w, offs, NC, NH);
  moe_gemm_kernel<0, 0><<<dim3(NC / 128, NN / 128, NE), 256, 0, stream>>>(
      hbuf, w2t, eo, slot_token, slot_w, offs, NH, NC);

  // weighted combine of each token's 2 expert rows
  combine_kernel<<<dim3(NN), 256, 0, stream>>>(eo, slot_of, y);
}

// Round 5
// 340.363 us; speedup vs baseline: 1.3989x; 1.1137x over previous
//
#include <hip/hip_runtime.h>
#include <hip/hip_bf16.h>

// Problem constants
#define NB 2
#define NT 2048
#define NC 1024          // C
#define NE 8             // experts
#define NH 2048          // H
#define NN (NB*NT)       // 4096 tokens
#define NSLOT (NN*2)     // 8192 routed (token,expert) slots

typedef short s16x8 __attribute__((ext_vector_type(8)));   // 8 bf16 (4 VGPRs)
typedef float f32x4 __attribute__((ext_vector_type(4)));

__device__ __forceinline__ unsigned short f2bf(float f) {
  union { float f; unsigned int u; } v; v.f = f;
  unsigned int r = v.u + 0x7FFFu + ((v.u >> 16) & 1u);  // RNE
  return (unsigned short)(r >> 16);
}

// async global->LDS, 16B/lane. LDS dest must be wave-uniform; HW adds lane*16.
#define GLOAD_LDS16(gp, lp) \
  __builtin_amdgcn_global_load_lds( \
      (const __attribute__((address_space(1))) void*)(gp), \
      (__attribute__((address_space(3))) void*)(lp), 16, 0, 0)

// ---------------- f32 -> bf16 elementwise (x) ----------------
__global__ void cvt_kernel(const float* __restrict__ in,
                           unsigned short* __restrict__ out, int n4) {
  int i = blockIdx.x * blockDim.x + threadIdx.x;
  if (i >= n4) return;
  float4 v = ((const float4*)in)[i];
  ushort4 o;
  o.x = f2bf(v.x); o.y = f2bf(v.y); o.z = f2bf(v.z); o.w = f2bf(v.w);
  ((ushort4*)out)[i] = o;
}

// -------- per-expert transpose + f32->bf16: in [R][Cc] -> out [Cc][R] --------
// 256 threads, 32x32 tile. float4 reads (128B/8-lane row), ushort4 stores.
__global__ void tcvt_kernel(const float* __restrict__ in,
                            unsigned short* __restrict__ out, int R, int Cc) {
  __shared__ unsigned short tile[32][33];
  const size_t eb = (size_t)blockIdx.z * R * Cc;
  const float* ip = in + eb;
  unsigned short* op = out + eb;
  const int c0 = blockIdx.x * 32, r0 = blockIdx.y * 32;
  const int t = threadIdx.x;
  {
    const int r = t >> 3, c4 = (t & 7) * 4;
    float4 v = *(const float4*)(ip + (size_t)(r0 + r) * Cc + c0 + c4);
    tile[r][c4 + 0] = f2bf(v.x); tile[r][c4 + 1] = f2bf(v.y);
    tile[r][c4 + 2] = f2bf(v.z); tile[r][c4 + 3] = f2bf(v.w);
  }
  __syncthreads();
  {
    const int c = t >> 3, q = (t & 7) * 4;
    ushort4 o;
    o.x = tile[q + 0][c]; o.y = tile[q + 1][c];
    o.z = tile[q + 2][c]; o.w = tile[q + 3][c];
    *(ushort4*)(op + (size_t)(c0 + c) * R + r0 + q) = o;
  }
}

// ---------------- router: scores = x@Wg, top-2, softmax (NO atomics) --------
__global__ void router_kernel(const float* __restrict__ x, const float* __restrict__ Wg,
                              int* __restrict__ tk_idx, float* __restrict__ tk_p) {
  int lane = threadIdx.x & 63;
  int n = blockIdx.x * 4 + (threadIdx.x >> 6);   // 4 waves/block, 1 token/wave
  const float4* xr = (const float4*)(x + (size_t)n * NC);
  float sc[NE];
  #pragma unroll
  for (int e = 0; e < NE; ++e) sc[e] = 0.f;
  #pragma unroll
  for (int i = 0; i < NC / 4 / 64; ++i) {        // 4 iters of float4
    int c4 = i * 64 + lane;                       // float4 index; c = c4*4
    float4 xv = xr[c4];
    const float4* wr = (const float4*)(Wg + (size_t)c4 * 4 * NE);
    #pragma unroll
    for (int j = 0; j < 4; ++j) {
      float xj = (j == 0) ? xv.x : (j == 1) ? xv.y : (j == 2) ? xv.z : xv.w;
      float4 w0 = wr[j * 2], w1 = wr[j * 2 + 1];
      sc[0] += xj * w0.x; sc[1] += xj * w0.y; sc[2] += xj * w0.z; sc[3] += xj * w0.w;
      sc[4] += xj * w1.x; sc[5] += xj * w1.y; sc[6] += xj * w1.z; sc[7] += xj * w1.w;
    }
  }
  #pragma unroll
  for (int e = 0; e < NE; ++e) {
    float v = sc[e];
    for (int s = 32; s >= 1; s >>= 1) v += __shfl_xor(v, s);
    sc[e] = v;
  }
  if (lane == 0) {
    int i0 = 0;
    #pragma unroll
    for (int e = 1; e < NE; ++e) if (sc[e] > sc[i0]) i0 = e;   // first-on-tie like lax.top_k
    int i1 = (i0 == 0) ? 1 : 0;
    #pragma unroll
    for (int e = 0; e < NE; ++e) if (e != i0 && sc[e] > sc[i1]) i1 = e;
    float e1 = __expf(sc[i1] - sc[i0]);
    float inv = 1.f / (1.f + e1);
    tk_idx[n * 2] = i0; tk_idx[n * 2 + 1] = i1;
    tk_p[n * 2] = inv;  tk_p[n * 2 + 1] = e1 * inv;
  }
}

// ------- single-block scan+scatter: ballot histogram, zero atomics ----------
// 256 threads = 4 waves; each wave owns 32 chunks of 64 entries (NSLOT=8192).
__global__ void route_scan_scatter(const int* __restrict__ tk_idx,
                                   const float* __restrict__ tk_p,
                                   int* __restrict__ offs,
                                   int* __restrict__ slot_token,
                                   float* __restrict__ slot_w,
                                   int* __restrict__ slot_of) {
  __shared__ int wcnt[4][NE];
  __shared__ int basel[4][NE];
  const int lane = threadIdx.x & 63, w = threadIdx.x >> 6;
  const unsigned long long lt = (1ull << lane) - 1ull;

  // phase 1: per-wave expert histogram via ballots
  int cnt0 = 0, cnt1 = 0, cnt2 = 0, cnt3 = 0, cnt4 = 0, cnt5 = 0, cnt6 = 0, cnt7 = 0;
  for (int ch = 0; ch < 32; ++ch) {
    int entry = (w * 32 + ch) * 64 + lane;
    int em = tk_idx[entry];
    cnt0 += __popcll(__ballot(em == 0));
    cnt1 += __popcll(__ballot(em == 1));
    cnt2 += __popcll(__ballot(em == 2));
    cnt3 += __popcll(__ballot(em == 3));
    cnt4 += __popcll(__ballot(em == 4));
    cnt5 += __popcll(__ballot(em == 5));
    cnt6 += __popcll(__ballot(em == 6));
    cnt7 += __popcll(__ballot(em == 7));
  }
  if (lane < NE) {
    int v = 0;
    if (lane == 0) v = cnt0; if (lane == 1) v = cnt1;
    if (lane == 2) v = cnt2; if (lane == 3) v = cnt3;
    if (lane == 4) v = cnt4; if (lane == 5) v = cnt5;
    if (lane == 6) v = cnt6; if (lane == 7) v = cnt7;
    wcnt[w][lane] = v;
  }
  __syncthreads();

  // phase 2: serial scan over 4x8 (thread 0)
  if (threadIdx.x == 0) {
    int a = 0;
    for (int e = 0; e < NE; ++e) {
      offs[e] = a;
      int s = a;
      for (int w2 = 0; w2 < 4; ++w2) { basel[w2][e] = s; s += wcnt[w2][e]; }
      a = s;
    }
    offs[NE] = a;   // == NSLOT
  }
  __syncthreads();

  // phase 3: assign positions (stable within wave; order is irrelevant anyway)
  int rb0 = basel[w][0], rb1 = basel[w][1], rb2 = basel[w][2], rb3 = basel[w][3];
  int rb4 = basel[w][4], rb5 = basel[w][5], rb6 = basel[w][6], rb7 = basel[w][7];
  for (int ch = 0; ch < 32; ++ch) {
    int entry = (w * 32 + ch) * 64 + lane;
    int em = tk_idx[entry];
    int pos = 0;
    unsigned long long m;
    m = __ballot(em == 0); if (em == 0) pos = rb0 + __popcll(m & lt); rb0 += __popcll(m);
    m = __ballot(em == 1); if (em == 1) pos = rb1 + __popcll(m & lt); rb1 += __popcll(m);
    m = __ballot(em == 2); if (em == 2) pos = rb2 + __popcll(m & lt); rb2 += __popcll(m);
    m = __ballot(em == 3); if (em == 3) pos = rb3 + __popcll(m & lt); rb3 += __popcll(m);
    m = __ballot(em == 4); if (em == 4) pos = rb4 + __popcll(m & lt); rb4 += __popcll(m);
    m = __ballot(em == 5); if (em == 5) pos = rb5 + __popcll(m & lt); rb5 += __popcll(m);
    m = __ballot(em == 6); if (em == 6) pos = rb6 + __popcll(m & lt); rb6 += __popcll(m);
    m = __ballot(em == 7); if (em == 7) pos = rb7 + __popcll(m & lt); rb7 += __popcll(m);
    slot_token[pos] = entry >> 1;
    slot_w[pos] = tk_p[entry];
    slot_of[entry] = pos;
  }
}

// ---------------- grouped GEMM, BK=64 + XOR quarter swizzle ----------------
// A [*][K] bf16 (rows gathered via slot_token if GATHER else direct slot rows)
// Bt [NE][Nn][K] bf16 (k-contiguous = pre-transposed weight)
// LDS tiles [128 rows][128 B]; LDS[row][q] holds global quarter q^(row&7)
// (staged by pre-swizzling the per-lane GLOBAL source; LDS dest stays linear).
// SILU=1: Out bf16 [NSLOT][Nn] = silu(A@B);  SILU=0: Out f32 = slot_w * (A@B)
template <int SILU, int GATHER>
__global__ __launch_bounds__(256, 2) void moe_gemm_kernel(
    const unsigned short* __restrict__ A, const unsigned short* __restrict__ Bt,
    void* __restrict__ Out, const int* __restrict__ slot_token,
    const float* __restrict__ slot_w, const int* __restrict__ offs, int K, int Nn) {
  __shared__ unsigned short lds_a[128 * 64];   // 16 KB
  __shared__ unsigned short lds_b[128 * 64];   // 16 KB
  const int e = blockIdx.z;
  const int off = offs[e];
  const int me = offs[e + 1] - off;
  const int rbase = blockIdx.y * 128;
  if (rbase >= me) return;                  // early-exit beyond this expert's rows
  const int n0 = blockIdx.x * 128;
  const int tid = threadIdx.x, lane = tid & 63, w = tid >> 6;
  const int wm = w >> 1, wn = w & 1;        // 2x2 wave grid, 64x64 out per wave

  // staging geometry: wave w covers tile rows [w*32, w*32+32), 4 issues of 8 rows.
  // lane: row-in-issue lr = lane>>3, quarter lq = lane&7; source quarter = lq^lr.
  const int lr = lane >> 3;
  const int lq = lane & 7;
  const int sq = (lq ^ lr) * 16;            // swizzled byte offset in 128B k-window
  const char* srcA[4];
  const char* srcB[4];
  #pragma unroll
  for (int i = 0; i < 4; ++i) {
    const int gr = rbase + w * 32 + i * 8 + lr;
    int ar;
    if (GATHER) ar = (gr < me) ? slot_token[off + gr] : 0;
    else        ar = (gr < me) ? (off + gr) : 0;
    srcA[i] = (const char*)(A + (size_t)ar * K) + sq;
    const int br = n0 + w * 32 + i * 8 + lr;
    srcB[i] = (const char*)(Bt + ((size_t)e * Nn + br) * K) + sq;
  }
  char* la = (char*)lds_a;
  char* lb = (char*)lds_b;

  f32x4 zero = {0.f, 0.f, 0.f, 0.f};
  f32x4 acc[4][4];
  #pragma unroll
  for (int m = 0; m < 4; ++m)
    #pragma unroll
    for (int n = 0; n < 4; ++n) acc[m][n] = zero;

  // fragment read bases (row stride 128 B). Fragment row&7 == lane&7, so the
  // de-swizzle XOR is a per-lane constant per k-half.
  const int ra = (wm * 64 + (lane & 15)) * 128;
  const int rb = (wn * 64 + (lane & 15)) * 128;
  const int qs0 = (((lane >> 4) + 0) ^ (lane & 7)) * 16;   // ks=0: quarters 0..3
  const int qs1 = (((lane >> 4) + 4) ^ (lane & 7)) * 16;   // ks=1: quarters 4..7

  for (int k0 = 0; k0 < K; k0 += 64) {
    const int kb = k0 * 2;
    #pragma unroll
    for (int i = 0; i < 4; ++i) GLOAD_LDS16(srcA[i] + kb, la + w * 4096 + i * 1024);
    #pragma unroll
    for (int i = 0; i < 4; ++i) GLOAD_LDS16(srcB[i] + kb, lb + w * 4096 + i * 1024);
    __syncthreads();   // compiler drains vmcnt(0) before barrier
    #pragma unroll
    for (int ks = 0; ks < 2; ++ks) {
      const int qo = ks ? qs1 : qs0;
      s16x8 a[4], b[4];
      #pragma unroll
      for (int m = 0; m < 4; ++m) a[m] = *(const s16x8*)(la + ra + m * 2048 + qo);
      #pragma unroll
      for (int n = 0; n < 4; ++n) b[n] = *(const s16x8*)(lb + rb + n * 2048 + qo);
      #pragma unroll
      for (int m = 0; m < 4; ++m)
        #pragma unroll
        for (int n = 0; n < 4; ++n)
          acc[m][n] = __builtin_amdgcn_mfma_f32_16x16x32_bf16(a[m], b[n], acc[m][n], 0, 0, 0);
    }
    __syncthreads();
  }

  // epilogue: D row=(lane>>4)*4+r, col=lane&15 (measured layout)
  if (SILU) {
    unsigned short* O = (unsigned short*)Out;
    #pragma unroll
    for (int m = 0; m < 4; ++m)
      #pragma unroll
      for (int r = 0; r < 4; ++r) {
        int row = wm * 64 + m * 16 + ((lane >> 4) << 2) + r;
        if (rbase + row < me) {
          size_t base = (size_t)(off + rbase + row) * Nn + n0 + wn * 64 + (lane & 15);
          #pragma unroll
          for (int n = 0; n < 4; ++n) {
            float v = acc[m][n][r];
            O[base + n * 16] = f2bf(v / (1.f + __expf(-v)));   // silu
          }
        }
      }
  } else {
    float* O = (float*)Out;
    #pragma unroll
    for (int m = 0; m < 4; ++m)
      #pragma unroll
      for (int r = 0; r < 4; ++r) {
        int row = wm * 64 + m * 16 + ((lane >> 4) << 2) + r;
        if (rbase + row < me) {
          float p = slot_w[off + rbase + row];
          size_t base = (size_t)(off + rbase + row) * Nn + n0 + wn * 64 + (lane & 15);
          #pragma unroll
          for (int n = 0; n < 4; ++n) O[base + n * 16] = p * acc[m][n][r];
        }
      }
  }
}

// ---------------- combine the 2 expert outputs per token ----------------
__global__ void combine_kernel(const float* __restrict__ Eo, const int* __restrict__ slot_of,
                               float* __restrict__ y) {
  int n = blockIdx.x;
  int t = threadIdx.x;
  int s0 = slot_of[n * 2], s1 = slot_of[n * 2 + 1];
  float4 va = ((const float4*)(Eo + (size_t)s0 * NC))[t];
  float4 vb = ((const float4*)(Eo + (size_t)s1 * NC))[t];
  float4 o;
  o.x = va.x + vb.x; o.y = va.y + vb.y; o.z = va.z + vb.z; o.w = va.w + vb.w;
  ((float4*)(y + (size_t)n * NC))[t] = o;
}

extern "C" void kernel_launch(void* const* d_in, const int* in_sizes, int n_in,
                              void* d_out, int out_size, void* d_ws, size_t ws_size,
                              hipStream_t stream) {
  const float* x  = (const float*)d_in[0];
  const float* Wg = (const float*)d_in[1];
  const float* W1 = (const float*)d_in[2];
  const float* W2 = (const float*)d_in[3];
  float* y = (float*)d_out;

  char* p = (char*)d_ws;
  auto carve = [&](size_t bytes) {
    char* r = p;
    p += (bytes + 255) & ~(size_t)255;
    return r;
  };
  unsigned short* xbf  = (unsigned short*)carve((size_t)NN * NC * 2);     // 8.4 MB
  unsigned short* w1t  = (unsigned short*)carve((size_t)NE * NH * NC * 2); // 33.6 MB [E][H][C]
  unsigned short* w2t  = (unsigned short*)carve((size_t)NE * NC * NH * 2); // 33.6 MB [E][C][H]
  unsigned short* hbuf = (unsigned short*)carve((size_t)NSLOT * NH * 2);   // 33.6 MB
  float* eo = (float*)w1t;  // alias: W1t dead after gemm1; Eo written in gemm2 (same 33.6 MB)
  int*   tk_idx     = (int*)carve(NSLOT * 4);
  float* tk_p       = (float*)carve(NSLOT * 4);
  int*   slot_token = (int*)carve(NSLOT * 4);
  float* slot_w     = (float*)carve(NSLOT * 4);
  int*   slot_of    = (int*)carve(NSLOT * 4);
  int*   offs       = (int*)carve((NE + 1) * 4);

  // dtype/layout conversions
  cvt_kernel<<<dim3(NN * NC / 4 / 256), 256, 0, stream>>>(x, xbf, NN * NC / 4);
  tcvt_kernel<<<dim3(NH / 32, NC / 32, NE), 256, 0, stream>>>(W1, w1t, NC, NH);
  tcvt_kernel<<<dim3(NC / 32, NH / 32, NE), 256, 0, stream>>>(W2, w2t, NH, NC);

  // routing (atomic-free)
  router_kernel<<<dim3(NN / 4), 256, 0, stream>>>(x, Wg, tk_idx, tk_p);
  route_scan_scatter<<<1, 256, 0, stream>>>(tk_idx, tk_p, offs,
                                            slot_token, slot_w, slot_of);

  // expert GEMMs (grouped, early-exit tiles beyond each expert's row count)
  moe_gemm_kernel<1, 1><<<dim3(NH / 128, NN / 128, NE), 256, 0, stream>>>(
      xbf, w1t, hbuf, slot_token, slot_w, offs, NC, NH);
  moe_gemm_kernel<0, 0><<<dim3(NC / 128, NN / 128, NE), 256, 0, stream>>>(
      hbuf, w2t, eo, slot_token, slot_w, offs, NH, NC);

  // weighted combine of each token's 2 expert rows
  combine_kernel<<<dim3(NN), 256, 0, stream>>>(eo, slot_of, y);
}

// Round 7
// 324.671 us; speedup vs baseline: 1.4665x; 1.0483x over previous
//
#include <hip/hip_runtime.h>
#include <hip/hip_bf16.h>

// Problem constants
#define NB 2
#define NT 2048
#define NC 1024          // C
#define NE 8             // experts
#define NH 2048          // H
#define NN (NB*NT)       // 4096 tokens
#define NSLOT (NN*2)     // 8192 routed (token,expert) slots

typedef short s16x8 __attribute__((ext_vector_type(8)));   // 8 bf16 (4 VGPRs)
typedef float f32x4 __attribute__((ext_vector_type(4)));

__device__ __forceinline__ unsigned short f2bf(float f) {
  union { float f; unsigned int u; } v; v.f = f;
  unsigned int r = v.u + 0x7FFFu + ((v.u >> 16) & 1u);  // RNE
  return (unsigned short)(r >> 16);
}

// async global->LDS, 16B/lane. LDS dest must be wave-uniform; HW adds lane*16.
#define GLOAD_LDS16(gp, lp) \
  __builtin_amdgcn_global_load_lds( \
      (const __attribute__((address_space(1))) void*)(gp), \
      (__attribute__((address_space(3))) void*)(lp), 16, 0, 0)

// ---------------- f32 -> bf16 elementwise (x) ----------------
__global__ void cvt_kernel(const float* __restrict__ in,
                           unsigned short* __restrict__ out, int n4) {
  int i = blockIdx.x * blockDim.x + threadIdx.x;
  if (i >= n4) return;
  float4 v = ((const float4*)in)[i];
  ushort4 o;
  o.x = f2bf(v.x); o.y = f2bf(v.y); o.z = f2bf(v.z); o.w = f2bf(v.w);
  ((ushort4*)out)[i] = o;
}

// -------- per-expert transpose + f32->bf16: in [R][Cc] -> out [Cc][R] --------
// 256 threads, 32x32 tile. float4 reads (128B/8-lane row), ushort4 stores.
__global__ void tcvt_kernel(const float* __restrict__ in,
                            unsigned short* __restrict__ out, int R, int Cc) {
  __shared__ unsigned short tile[32][33];
  const size_t eb = (size_t)blockIdx.z * R * Cc;
  const float* ip = in + eb;
  unsigned short* op = out + eb;
  const int c0 = blockIdx.x * 32, r0 = blockIdx.y * 32;
  const int t = threadIdx.x;
  {
    const int r = t >> 3, c4 = (t & 7) * 4;
    float4 v = *(const float4*)(ip + (size_t)(r0 + r) * Cc + c0 + c4);
    tile[r][c4 + 0] = f2bf(v.x); tile[r][c4 + 1] = f2bf(v.y);
    tile[r][c4 + 2] = f2bf(v.z); tile[r][c4 + 3] = f2bf(v.w);
  }
  __syncthreads();
  {
    const int c = t >> 3, q = (t & 7) * 4;
    ushort4 o;
    o.x = tile[q + 0][c]; o.y = tile[q + 1][c];
    o.z = tile[q + 2][c]; o.w = tile[q + 3][c];
    *(ushort4*)(op + (size_t)(c0 + c) * R + r0 + q) = o;
  }
}

// ---------------- router: scores = x@Wg, top-2, softmax (NO atomics) --------
__global__ void router_kernel(const float* __restrict__ x, const float* __restrict__ Wg,
                              int* __restrict__ tk_idx, float* __restrict__ tk_p) {
  int lane = threadIdx.x & 63;
  int n = blockIdx.x * 4 + (threadIdx.x >> 6);   // 4 waves/block, 1 token/wave
  const float4* xr = (const float4*)(x + (size_t)n * NC);
  float sc[NE];
  #pragma unroll
  for (int e = 0; e < NE; ++e) sc[e] = 0.f;
  #pragma unroll
  for (int i = 0; i < NC / 4 / 64; ++i) {        // 4 iters of float4
    int c4 = i * 64 + lane;                       // float4 index; c = c4*4
    float4 xv = xr[c4];
    const float4* wr = (const float4*)(Wg + (size_t)c4 * 4 * NE);
    #pragma unroll
    for (int j = 0; j < 4; ++j) {
      float xj = (j == 0) ? xv.x : (j == 1) ? xv.y : (j == 2) ? xv.z : xv.w;
      float4 w0 = wr[j * 2], w1 = wr[j * 2 + 1];
      sc[0] += xj * w0.x; sc[1] += xj * w0.y; sc[2] += xj * w0.z; sc[3] += xj * w0.w;
      sc[4] += xj * w1.x; sc[5] += xj * w1.y; sc[6] += xj * w1.z; sc[7] += xj * w1.w;
    }
  }
  #pragma unroll
  for (int e = 0; e < NE; ++e) {
    float v = sc[e];
    for (int s = 32; s >= 1; s >>= 1) v += __shfl_xor(v, s);
    sc[e] = v;
  }
  if (lane == 0) {
    int i0 = 0;
    #pragma unroll
    for (int e = 1; e < NE; ++e) if (sc[e] > sc[i0]) i0 = e;   // first-on-tie like lax.top_k
    int i1 = (i0 == 0) ? 1 : 0;
    #pragma unroll
    for (int e = 0; e < NE; ++e) if (e != i0 && sc[e] > sc[i1]) i1 = e;
    float e1 = __expf(sc[i1] - sc[i0]);
    float inv = 1.f / (1.f + e1);
    tk_idx[n * 2] = i0; tk_idx[n * 2 + 1] = i1;
    tk_p[n * 2] = inv;  tk_p[n * 2 + 1] = e1 * inv;
  }
}

// ------- single-block scan+scatter: ballot histogram, zero atomics ----------
// 256 threads = 4 waves; each wave owns 32 chunks of 64 entries (NSLOT=8192).
__global__ void route_scan_scatter(const int* __restrict__ tk_idx,
                                   const float* __restrict__ tk_p,
                                   int* __restrict__ offs,
                                   int* __restrict__ slot_token,
                                   float* __restrict__ slot_w,
                                   int* __restrict__ slot_of) {
  __shared__ int wcnt[4][NE];
  __shared__ int basel[4][NE];
  const int lane = threadIdx.x & 63, w = threadIdx.x >> 6;
  const unsigned long long lt = (1ull << lane) - 1ull;

  // phase 1: per-wave expert histogram via ballots
  int cnt0 = 0, cnt1 = 0, cnt2 = 0, cnt3 = 0, cnt4 = 0, cnt5 = 0, cnt6 = 0, cnt7 = 0;
  for (int ch = 0; ch < 32; ++ch) {
    int entry = (w * 32 + ch) * 64 + lane;
    int em = tk_idx[entry];
    cnt0 += __popcll(__ballot(em == 0));
    cnt1 += __popcll(__ballot(em == 1));
    cnt2 += __popcll(__ballot(em == 2));
    cnt3 += __popcll(__ballot(em == 3));
    cnt4 += __popcll(__ballot(em == 4));
    cnt5 += __popcll(__ballot(em == 5));
    cnt6 += __popcll(__ballot(em == 6));
    cnt7 += __popcll(__ballot(em == 7));
  }
  if (lane < NE) {
    int v = 0;
    if (lane == 0) v = cnt0; if (lane == 1) v = cnt1;
    if (lane == 2) v = cnt2; if (lane == 3) v = cnt3;
    if (lane == 4) v = cnt4; if (lane == 5) v = cnt5;
    if (lane == 6) v = cnt6; if (lane == 7) v = cnt7;
    wcnt[w][lane] = v;
  }
  __syncthreads();

  // phase 2: serial scan over 4x8 (thread 0)
  if (threadIdx.x == 0) {
    int a = 0;
    for (int e = 0; e < NE; ++e) {
      offs[e] = a;
      int s = a;
      for (int w2 = 0; w2 < 4; ++w2) { basel[w2][e] = s; s += wcnt[w2][e]; }
      a = s;
    }
    offs[NE] = a;   // == NSLOT
  }
  __syncthreads();

  // phase 3: assign positions (stable within wave; order is irrelevant anyway)
  int rb0 = basel[w][0], rb1 = basel[w][1], rb2 = basel[w][2], rb3 = basel[w][3];
  int rb4 = basel[w][4], rb5 = basel[w][5], rb6 = basel[w][6], rb7 = basel[w][7];
  for (int ch = 0; ch < 32; ++ch) {
    int entry = (w * 32 + ch) * 64 + lane;
    int em = tk_idx[entry];
    int pos = 0;
    unsigned long long m;
    m = __ballot(em == 0); if (em == 0) pos = rb0 + __popcll(m & lt); rb0 += __popcll(m);
    m = __ballot(em == 1); if (em == 1) pos = rb1 + __popcll(m & lt); rb1 += __popcll(m);
    m = __ballot(em == 2); if (em == 2) pos = rb2 + __popcll(m & lt); rb2 += __popcll(m);
    m = __ballot(em == 3); if (em == 3) pos = rb3 + __popcll(m & lt); rb3 += __popcll(m);
    m = __ballot(em == 4); if (em == 4) pos = rb4 + __popcll(m & lt); rb4 += __popcll(m);
    m = __ballot(em == 5); if (em == 5) pos = rb5 + __popcll(m & lt); rb5 += __popcll(m);
    m = __ballot(em == 6); if (em == 6) pos = rb6 + __popcll(m & lt); rb6 += __popcll(m);
    m = __ballot(em == 7); if (em == 7) pos = rb7 + __popcll(m & lt); rb7 += __popcll(m);
    slot_token[pos] = entry >> 1;
    slot_w[pos] = tk_p[entry];
    slot_of[entry] = pos;
  }
}

// -------- grouped GEMM: BK=64, XOR quarter swizzle, XCD-chunk swizzle -------
// Single-buffer 2-barrier K-loop (round-5-proven race-free structure).
// A [*][K] bf16 (rows gathered via slot_token if GATHER else direct slot rows)
// Bt [NE][Nn][K] bf16 (k-contiguous = pre-transposed weight)
// SILU=1: Out bf16 [NSLOT][Nn] = silu(A@B);  SILU=0: Out f32 = slot_w * (A@B)
template <int SILU, int GATHER>
__global__ __launch_bounds__(256, 2) void moe_gemm_kernel(
    const unsigned short* __restrict__ A, const unsigned short* __restrict__ Bt,
    void* __restrict__ Out, const int* __restrict__ slot_token,
    const float* __restrict__ slot_w, const int* __restrict__ offs, int K, int Nn) {
  __shared__ unsigned short lds_a[128 * 64];   // 16 KB
  __shared__ unsigned short lds_b[128 * 64];   // 16 KB

  // XCD-chunk swizzle: flat id -> (n-tile, m-tile, expert) such that XCD x
  // (flat%8 round-robin) executes exactly expert x's blocks, with all gx
  // n-tiles of one (m,e) chunk contiguous on that XCD (A-tile L2 reuse; the
  // expert's 4.2MB B panel stays L2-resident). Bijective: nwg % (8*gx) == 0
  // and gy*gz == 256.
  const int gx = gridDim.x;
  const int h = blockIdx.x + gx * (blockIdx.y + gridDim.y * blockIdx.z);
  const int xcd = h & 7, s = h >> 3;
  const int n_idx = s % gx;
  const int chunk = xcd * ((gridDim.y * gridDim.z) >> 3) + s / gx;
  const int by = chunk & (gridDim.y - 1);     // gy = 32 (pow2)
  const int e = chunk >> 5;                   // / gy

  const int off = offs[e];
  const int me = offs[e + 1] - off;
  const int rbase = by * 128;
  if (rbase >= me) return;                  // early-exit beyond this expert's rows
  const int n0 = n_idx * 128;
  const int tid = threadIdx.x, lane = tid & 63, w = tid >> 6;
  const int wm = w >> 1, wn = w & 1;        // 2x2 wave grid, 64x64 out per wave

  // staging geometry: wave w covers tile rows [w*32, w*32+32), 4 issues of 8 rows.
  // lane: row-in-issue lr = lane>>3, quarter lq = lane&7; source quarter = lq^lr.
  const int lr = lane >> 3;
  const int lq = lane & 7;
  const int sq = (lq ^ lr) * 16;            // swizzled byte offset in 128B k-window
  const char* srcA[4];
  const char* srcB[4];
  #pragma unroll
  for (int i = 0; i < 4; ++i) {
    const int gr = rbase + w * 32 + i * 8 + lr;
    int ar;
    if (GATHER) ar = (gr < me) ? slot_token[off + gr] : 0;
    else        ar = (gr < me) ? (off + gr) : 0;
    srcA[i] = (const char*)(A + (size_t)ar * K) + sq;
    const int br = n0 + w * 32 + i * 8 + lr;
    srcB[i] = (const char*)(Bt + ((size_t)e * Nn + br) * K) + sq;
  }
  char* la = (char*)lds_a;
  char* lb = (char*)lds_b;

  f32x4 zero = {0.f, 0.f, 0.f, 0.f};
  f32x4 acc[4][4];
  #pragma unroll
  for (int m = 0; m < 4; ++m)
    #pragma unroll
    for (int n = 0; n < 4; ++n) acc[m][n] = zero;

  // fragment read bases (row stride 128 B). Fragment row&7 == lane&7, so the
  // de-swizzle XOR is a per-lane constant per k-half.
  const int ra = (wm * 64 + (lane & 15)) * 128;
  const int rb = (wn * 64 + (lane & 15)) * 128;
  const int qs0 = (((lane >> 4) + 0) ^ (lane & 7)) * 16;   // ks=0: quarters 0..3
  const int qs1 = (((lane >> 4) + 4) ^ (lane & 7)) * 16;   // ks=1: quarters 4..7

  for (int k0 = 0; k0 < K; k0 += 64) {
    const int kb = k0 * 2;
    #pragma unroll
    for (int i = 0; i < 4; ++i) GLOAD_LDS16(srcA[i] + kb, la + w * 4096 + i * 1024);
    #pragma unroll
    for (int i = 0; i < 4; ++i) GLOAD_LDS16(srcB[i] + kb, lb + w * 4096 + i * 1024);
    __syncthreads();   // full drain before barrier (proven race-free in r5)
    #pragma unroll
    for (int ks = 0; ks < 2; ++ks) {
      const int qo = ks ? qs1 : qs0;
      s16x8 a[4], b[4];
      #pragma unroll
      for (int m = 0; m < 4; ++m) a[m] = *(const s16x8*)(la + ra + m * 2048 + qo);
      #pragma unroll
      for (int n = 0; n < 4; ++n) b[n] = *(const s16x8*)(lb + rb + n * 2048 + qo);
      #pragma unroll
      for (int m = 0; m < 4; ++m)
        #pragma unroll
        for (int n = 0; n < 4; ++n)
          acc[m][n] = __builtin_amdgcn_mfma_f32_16x16x32_bf16(a[m], b[n], acc[m][n], 0, 0, 0);
    }
    __syncthreads();
  }

  // epilogue: D row=(lane>>4)*4+r, col=lane&15 (measured layout)
  if (SILU) {
    unsigned short* O = (unsigned short*)Out;
    #pragma unroll
    for (int m = 0; m < 4; ++m)
      #pragma unroll
      for (int r = 0; r < 4; ++r) {
        int row = wm * 64 + m * 16 + ((lane >> 4) << 2) + r;
        if (rbase + row < me) {
          size_t base = (size_t)(off + rbase + row) * Nn + n0 + wn * 64 + (lane & 15);
          #pragma unroll
          for (int n = 0; n < 4; ++n) {
            float v = acc[m][n][r];
            O[base + n * 16] = f2bf(v / (1.f + __expf(-v)));   // silu
          }
        }
      }
  } else {
    float* O = (float*)Out;
    #pragma unroll
    for (int m = 0; m < 4; ++m)
      #pragma unroll
      for (int r = 0; r < 4; ++r) {
        int row = wm * 64 + m * 16 + ((lane >> 4) << 2) + r;
        if (rbase + row < me) {
          float p = slot_w[off + rbase + row];
          size_t base = (size_t)(off + rbase + row) * Nn + n0 + wn * 64 + (lane & 15);
          #pragma unroll
          for (int n = 0; n < 4; ++n) O[base + n * 16] = p * acc[m][n][r];
        }
      }
  }
}

// ---------------- combine the 2 expert outputs per token ----------------
__global__ void combine_kernel(const float* __restrict__ Eo, const int* __restrict__ slot_of,
                               float* __restrict__ y) {
  int n = blockIdx.x;
  int t = threadIdx.x;
  int s0 = slot_of[n * 2], s1 = slot_of[n * 2 + 1];
  float4 va = ((const float4*)(Eo + (size_t)s0 * NC))[t];
  float4 vb = ((const float4*)(Eo + (size_t)s1 * NC))[t];
  float4 o;
  o.x = va.x + vb.x; o.y = va.y + vb.y; o.z = va.z + vb.z; o.w = va.w + vb.w;
  ((float4*)(y + (size_t)n * NC))[t] = o;
}

extern "C" void kernel_launch(void* const* d_in, const int* in_sizes, int n_in,
                              void* d_out, int out_size, void* d_ws, size_t ws_size,
                              hipStream_t stream) {
  const float* x  = (const float*)d_in[0];
  const float* Wg = (const float*)d_in[1];
  const float* W1 = (const float*)d_in[2];
  const float* W2 = (const float*)d_in[3];
  float* y = (float*)d_out;

  char* p = (char*)d_ws;
  auto carve = [&](size_t bytes) {
    char* r = p;
    p += (bytes + 255) & ~(size_t)255;
    return r;
  };
  unsigned short* xbf  = (unsigned short*)carve((size_t)NN * NC * 2);     // 8.4 MB
  unsigned short* w1t  = (unsigned short*)carve((size_t)NE * NH * NC * 2); // 33.6 MB [E][H][C]
  unsigned short* w2t  = (unsigned short*)carve((size_t)NE * NC * NH * 2); // 33.6 MB [E][C][H]
  unsigned short* hbuf = (unsigned short*)carve((size_t)NSLOT * NH * 2);   // 33.6 MB
  float* eo = (float*)w1t;  // alias: W1t dead after gemm1; Eo written in gemm2 (same 33.6 MB)
  int*   tk_idx     = (int*)carve(NSLOT * 4);
  float* tk_p       = (float*)carve(NSLOT * 4);
  int*   slot_token = (int*)carve(NSLOT * 4);
  float* slot_w     = (float*)carve(NSLOT * 4);
  int*   slot_of    = (int*)carve(NSLOT * 4);
  int*   offs       = (int*)carve((NE + 1) * 4);

  // dtype/layout conversions
  cvt_kernel<<<dim3(NN * NC / 4 / 256), 256, 0, stream>>>(x, xbf, NN * NC / 4);
  tcvt_kernel<<<dim3(NH / 32, NC / 32, NE), 256, 0, stream>>>(W1, w1t, NC, NH);
  tcvt_kernel<<<dim3(NC / 32, NH / 32, NE), 256, 0, stream>>>(W2, w2t, NH, NC);

  // routing (atomic-free)
  router_kernel<<<dim3(NN / 4), 256, 0, stream>>>(x, Wg, tk_idx, tk_p);
  route_scan_scatter<<<1, 256, 0, stream>>>(tk_idx, tk_p, offs,
                                            slot_token, slot_w, slot_of);

  // expert GEMMs (grouped, early-exit tiles beyond each expert's row count)
  moe_gemm_kernel<1, 1><<<dim3(NH / 128, NN / 128, NE), 256, 0, stream>>>(
      xbf, w1t, hbuf, slot_token, slot_w, offs, NC, NH);
  moe_gemm_kernel<0, 0><<<dim3(NC / 128, NN / 128, NE), 256, 0, stream>>>(
      hbuf, w2t, eo, slot_token, slot_w, offs, NH, NC);

  // weighted combine of each token's 2 expert rows
  combine_kernel<<<dim3(NN), 256, 0, stream>>>(eo, slot_of, y);
}

// Round 8
// 299.972 us; speedup vs baseline: 1.5872x; 1.0823x over previous
//
#include <hip/hip_runtime.h>
#include <hip/hip_bf16.h>

// Problem constants
#define NB 2
#define NT 2048
#define NC 1024          // C
#define NE 8             // experts
#define NH 2048          // H
#define NN (NB*NT)       // 4096 tokens
#define NSLOT (NN*2)     // 8192 routed (token,expert) slots

typedef short s16x8 __attribute__((ext_vector_type(8)));   // 8 bf16 (4 VGPRs)
typedef unsigned short u16x8 __attribute__((ext_vector_type(8)));
typedef float f32x4 __attribute__((ext_vector_type(4)));

__device__ __forceinline__ unsigned short f2bf(float f) {
  union { float f; unsigned int u; } v; v.f = f;
  unsigned int r = v.u + 0x7FFFu + ((v.u >> 16) & 1u);  // RNE
  return (unsigned short)(r >> 16);
}

// async global->LDS, 16B/lane. LDS dest must be wave-uniform; HW adds lane*16.
#define GLOAD_LDS16(gp, lp) \
  __builtin_amdgcn_global_load_lds( \
      (const __attribute__((address_space(1))) void*)(gp), \
      (__attribute__((address_space(3))) void*)(lp), 16, 0, 0)

// -------- per-expert transpose + f32->bf16: in [R][Cc] -> out [Cc][R] --------
// 64x64 tile, 256 threads. Phase 1: float4 reads, transposed scalar LDS
// stores. Phase 2: ds_read_b128 (16B-aligned, pad 72) + ushort8 global
// writes -> 128B contiguous per 8 lanes.
__global__ void tcvt64_kernel(const float* __restrict__ in,
                              unsigned short* __restrict__ out, int R, int Cc) {
  __shared__ unsigned short tileT[64][72];   // transposed tile, 144B row stride
  const size_t eb = (size_t)blockIdx.z * R * Cc;
  const float* ip = in + eb;
  unsigned short* op = out + eb;
  const int c0 = blockIdx.x * 64, r0 = blockIdx.y * 64;
  const int t = threadIdx.x;
  #pragma unroll
  for (int i = 0; i < 4; ++i) {
    const int slot = i * 256 + t;
    const int r = slot >> 4, c4 = (slot & 15) * 4;
    float4 v = *(const float4*)(ip + (size_t)(r0 + r) * Cc + c0 + c4);
    tileT[c4 + 0][r] = f2bf(v.x); tileT[c4 + 1][r] = f2bf(v.y);
    tileT[c4 + 2][r] = f2bf(v.z); tileT[c4 + 3][r] = f2bf(v.w);
  }
  __syncthreads();
  #pragma unroll
  for (int i = 0; i < 2; ++i) {
    const int slot = i * 256 + t;
    const int c = slot >> 3, r8 = (slot & 7) * 8;
    u16x8 v = *(const u16x8*)&tileT[c][r8];
    *(u16x8*)(op + (size_t)(c0 + c) * R + r0 + r8) = v;
  }
}

// ------ router: scores = x@Wg, top-2 softmax; fused x f32->bf16 convert -----
__global__ void router_kernel(const float* __restrict__ x, const float* __restrict__ Wg,
                              unsigned short* __restrict__ xbf,
                              int* __restrict__ tk_idx, float* __restrict__ tk_p) {
  int lane = threadIdx.x & 63;
  int n = blockIdx.x * 4 + (threadIdx.x >> 6);   // 4 waves/block, 1 token/wave
  const float4* xr = (const float4*)(x + (size_t)n * NC);
  unsigned short* xo = xbf + (size_t)n * NC;
  float sc[NE];
  #pragma unroll
  for (int e = 0; e < NE; ++e) sc[e] = 0.f;
  #pragma unroll
  for (int i = 0; i < NC / 4 / 64; ++i) {        // 4 iters of float4
    int c4 = i * 64 + lane;                       // float4 index; c = c4*4
    float4 xv = xr[c4];
    ushort4 o;
    o.x = f2bf(xv.x); o.y = f2bf(xv.y); o.z = f2bf(xv.z); o.w = f2bf(xv.w);
    *(ushort4*)(xo + c4 * 4) = o;                 // fused bf16 conversion
    const float4* wr = (const float4*)(Wg + (size_t)c4 * 4 * NE);
    #pragma unroll
    for (int j = 0; j < 4; ++j) {
      float xj = (j == 0) ? xv.x : (j == 1) ? xv.y : (j == 2) ? xv.z : xv.w;
      float4 w0 = wr[j * 2], w1 = wr[j * 2 + 1];
      sc[0] += xj * w0.x; sc[1] += xj * w0.y; sc[2] += xj * w0.z; sc[3] += xj * w0.w;
      sc[4] += xj * w1.x; sc[5] += xj * w1.y; sc[6] += xj * w1.z; sc[7] += xj * w1.w;
    }
  }
  #pragma unroll
  for (int e = 0; e < NE; ++e) {
    float v = sc[e];
    for (int s = 32; s >= 1; s >>= 1) v += __shfl_xor(v, s);
    sc[e] = v;
  }
  if (lane == 0) {
    int i0 = 0;
    #pragma unroll
    for (int e = 1; e < NE; ++e) if (sc[e] > sc[i0]) i0 = e;   // first-on-tie like lax.top_k
    int i1 = (i0 == 0) ? 1 : 0;
    #pragma unroll
    for (int e = 0; e < NE; ++e) if (e != i0 && sc[e] > sc[i1]) i1 = e;
    float e1 = __expf(sc[i1] - sc[i0]);
    float inv = 1.f / (1.f + e1);
    tk_idx[n * 2] = i0; tk_idx[n * 2 + 1] = i1;
    tk_p[n * 2] = inv;  tk_p[n * 2 + 1] = e1 * inv;
  }
}

// ------- single-block scan+scatter: ballot histogram, zero atomics ----------
// 1024 threads = 16 waves; each wave owns 8 chunks of 64 entries (NSLOT=8192).
__global__ void route_scan_scatter(const int* __restrict__ tk_idx,
                                   const float* __restrict__ tk_p,
                                   int* __restrict__ offs,
                                   int* __restrict__ slot_token,
                                   float* __restrict__ slot_w,
                                   int* __restrict__ slot_of) {
  __shared__ int wcnt[16][NE];
  __shared__ int basel[16][NE];
  const int lane = threadIdx.x & 63, w = threadIdx.x >> 6;
  const unsigned long long lt = (1ull << lane) - 1ull;

  // phase 1: per-wave expert histogram via ballots
  int cnt0 = 0, cnt1 = 0, cnt2 = 0, cnt3 = 0, cnt4 = 0, cnt5 = 0, cnt6 = 0, cnt7 = 0;
  for (int ch = 0; ch < 8; ++ch) {
    int entry = (w * 8 + ch) * 64 + lane;
    int em = tk_idx[entry];
    cnt0 += __popcll(__ballot(em == 0));
    cnt1 += __popcll(__ballot(em == 1));
    cnt2 += __popcll(__ballot(em == 2));
    cnt3 += __popcll(__ballot(em == 3));
    cnt4 += __popcll(__ballot(em == 4));
    cnt5 += __popcll(__ballot(em == 5));
    cnt6 += __popcll(__ballot(em == 6));
    cnt7 += __popcll(__ballot(em == 7));
  }
  if (lane < NE) {
    int v = 0;
    if (lane == 0) v = cnt0; if (lane == 1) v = cnt1;
    if (lane == 2) v = cnt2; if (lane == 3) v = cnt3;
    if (lane == 4) v = cnt4; if (lane == 5) v = cnt5;
    if (lane == 6) v = cnt6; if (lane == 7) v = cnt7;
    wcnt[w][lane] = v;
  }
  __syncthreads();

  // phase 2: serial scan over 16x8 (thread 0)
  if (threadIdx.x == 0) {
    int a = 0;
    for (int e = 0; e < NE; ++e) {
      offs[e] = a;
      int s = a;
      for (int w2 = 0; w2 < 16; ++w2) { basel[w2][e] = s; s += wcnt[w2][e]; }
      a = s;
    }
    offs[NE] = a;   // == NSLOT
  }
  __syncthreads();

  // phase 3: assign positions (stable within wave; order is irrelevant anyway)
  int rb0 = basel[w][0], rb1 = basel[w][1], rb2 = basel[w][2], rb3 = basel[w][3];
  int rb4 = basel[w][4], rb5 = basel[w][5], rb6 = basel[w][6], rb7 = basel[w][7];
  for (int ch = 0; ch < 8; ++ch) {
    int entry = (w * 8 + ch) * 64 + lane;
    int em = tk_idx[entry];
    int pos = 0;
    unsigned long long m;
    m = __ballot(em == 0); if (em == 0) pos = rb0 + __popcll(m & lt); rb0 += __popcll(m);
    m = __ballot(em == 1); if (em == 1) pos = rb1 + __popcll(m & lt); rb1 += __popcll(m);
    m = __ballot(em == 2); if (em == 2) pos = rb2 + __popcll(m & lt); rb2 += __popcll(m);
    m = __ballot(em == 3); if (em == 3) pos = rb3 + __popcll(m & lt); rb3 += __popcll(m);
    m = __ballot(em == 4); if (em == 4) pos = rb4 + __popcll(m & lt); rb4 += __popcll(m);
    m = __ballot(em == 5); if (em == 5) pos = rb5 + __popcll(m & lt); rb5 += __popcll(m);
    m = __ballot(em == 6); if (em == 6) pos = rb6 + __popcll(m & lt); rb6 += __popcll(m);
    m = __ballot(em == 7); if (em == 7) pos = rb7 + __popcll(m & lt); rb7 += __popcll(m);
    slot_token[pos] = entry >> 1;
    slot_w[pos] = tk_p[entry];
    slot_of[entry] = pos;
  }
}

// -------- grouped GEMM: BK=64, XOR quarter swizzle, XCD-chunk swizzle -------
// Single-buffer 2-barrier K-loop (round-5-proven race-free structure).
// A [*][K] bf16 (rows gathered via slot_token if GATHER else direct slot rows)
// Bt [NE][Nn][K] bf16 (k-contiguous = pre-transposed weight)
// SILU=1: Out bf16 [NSLOT][Nn] = silu(A@B);  SILU=0: Out f32 = slot_w * (A@B)
template <int SILU, int GATHER>
__global__ __launch_bounds__(256, 4) void moe_gemm_kernel(
    const unsigned short* __restrict__ A, const unsigned short* __restrict__ Bt,
    void* __restrict__ Out, const int* __restrict__ slot_token,
    const float* __restrict__ slot_w, const int* __restrict__ offs, int K, int Nn) {
  __shared__ unsigned short lds_a[128 * 64];   // 16 KB
  __shared__ unsigned short lds_b[128 * 64];   // 16 KB

  // XCD-chunk swizzle: flat id -> (n-tile, m-tile, expert) such that XCD x
  // (flat%8 round-robin) executes exactly expert x's blocks, with all gx
  // n-tiles of one (m,e) chunk contiguous on that XCD (A-tile L2 reuse; the
  // expert's 4.2MB B panel stays L2-resident). Bijective: nwg % (8*gx) == 0
  // and gy*gz == 256.
  const int gx = gridDim.x;
  const int h = blockIdx.x + gx * (blockIdx.y + gridDim.y * blockIdx.z);
  const int xcd = h & 7, s = h >> 3;
  const int n_idx = s % gx;
  const int chunk = xcd * ((gridDim.y * gridDim.z) >> 3) + s / gx;
  const int by = chunk & (gridDim.y - 1);     // gy = 32 (pow2)
  const int e = chunk >> 5;                   // / gy

  const int off = offs[e];
  const int me = offs[e + 1] - off;
  const int rbase = by * 128;
  if (rbase >= me) return;                  // early-exit beyond this expert's rows
  const int n0 = n_idx * 128;
  const int tid = threadIdx.x, lane = tid & 63, w = tid >> 6;
  const int wm = w >> 1, wn = w & 1;        // 2x2 wave grid, 64x64 out per wave

  // staging geometry: wave w covers tile rows [w*32, w*32+32), 4 issues of 8 rows.
  // lane: row-in-issue lr = lane>>3, quarter lq = lane&7; source quarter = lq^lr.
  const int lr = lane >> 3;
  const int lq = lane & 7;
  const int sq = (lq ^ lr) * 16;            // swizzled byte offset in 128B k-window
  const char* srcA[4];
  const char* srcB[4];
  #pragma unroll
  for (int i = 0; i < 4; ++i) {
    const int gr = rbase + w * 32 + i * 8 + lr;
    int ar;
    if (GATHER) ar = (gr < me) ? slot_token[off + gr] : 0;
    else        ar = (gr < me) ? (off + gr) : 0;
    srcA[i] = (const char*)(A + (size_t)ar * K) + sq;
    const int br = n0 + w * 32 + i * 8 + lr;
    srcB[i] = (const char*)(Bt + ((size_t)e * Nn + br) * K) + sq;
  }
  char* la = (char*)lds_a;
  char* lb = (char*)lds_b;

  f32x4 zero = {0.f, 0.f, 0.f, 0.f};
  f32x4 acc[4][4];
  #pragma unroll
  for (int m = 0; m < 4; ++m)
    #pragma unroll
    for (int n = 0; n < 4; ++n) acc[m][n] = zero;

  // fragment read bases (row stride 128 B). Fragment row&7 == lane&7, so the
  // de-swizzle XOR is a per-lane constant per k-half.
  const int ra = (wm * 64 + (lane & 15)) * 128;
  const int rb = (wn * 64 + (lane & 15)) * 128;
  const int qs0 = (((lane >> 4) + 0) ^ (lane & 7)) * 16;   // ks=0: quarters 0..3
  const int qs1 = (((lane >> 4) + 4) ^ (lane & 7)) * 16;   // ks=1: quarters 4..7

  for (int k0 = 0; k0 < K; k0 += 64) {
    const int kb = k0 * 2;
    #pragma unroll
    for (int i = 0; i < 4; ++i) GLOAD_LDS16(srcA[i] + kb, la + w * 4096 + i * 1024);
    #pragma unroll
    for (int i = 0; i < 4; ++i) GLOAD_LDS16(srcB[i] + kb, lb + w * 4096 + i * 1024);
    __syncthreads();   // full drain before barrier (proven race-free in r5)
    #pragma unroll
    for (int ks = 0; ks < 2; ++ks) {
      const int qo = ks ? qs1 : qs0;
      s16x8 a[4], b[4];
      #pragma unroll
      for (int m = 0; m < 4; ++m) a[m] = *(const s16x8*)(la + ra + m * 2048 + qo);
      #pragma unroll
      for (int n = 0; n < 4; ++n) b[n] = *(const s16x8*)(lb + rb + n * 2048 + qo);
      #pragma unroll
      for (int m = 0; m < 4; ++m)
        #pragma unroll
        for (int n = 0; n < 4; ++n)
          acc[m][n] = __builtin_amdgcn_mfma_f32_16x16x32_bf16(a[m], b[n], acc[m][n], 0, 0, 0);
    }
    __syncthreads();
  }

  // epilogue: D row=(lane>>4)*4+r, col=lane&15 (measured layout)
  if (SILU) {
    unsigned short* O = (unsigned short*)Out;
    #pragma unroll
    for (int m = 0; m < 4; ++m)
      #pragma unroll
      for (int r = 0; r < 4; ++r) {
        int row = wm * 64 + m * 16 + ((lane >> 4) << 2) + r;
        if (rbase + row < me) {
          size_t base = (size_t)(off + rbase + row) * Nn + n0 + wn * 64 + (lane & 15);
          #pragma unroll
          for (int n = 0; n < 4; ++n) {
            float v = acc[m][n][r];
            O[base + n * 16] = f2bf(v / (1.f + __expf(-v)));   // silu
          }
        }
      }
  } else {
    float* O = (float*)Out;
    #pragma unroll
    for (int m = 0; m < 4; ++m)
      #pragma unroll
      for (int r = 0; r < 4; ++r) {
        int row = wm * 64 + m * 16 + ((lane >> 4) << 2) + r;
        if (rbase + row < me) {
          float p = slot_w[off + rbase + row];
          size_t base = (size_t)(off + rbase + row) * Nn + n0 + wn * 64 + (lane & 15);
          #pragma unroll
          for (int n = 0; n < 4; ++n) O[base + n * 16] = p * acc[m][n][r];
        }
      }
  }
}

// ---------------- combine the 2 expert outputs per token ----------------
__global__ void combine_kernel(const float* __restrict__ Eo, const int* __restrict__ slot_of,
                               float* __restrict__ y) {
  int n = blockIdx.x;
  int t = threadIdx.x;
  int s0 = slot_of[n * 2], s1 = slot_of[n * 2 + 1];
  float4 va = ((const float4*)(Eo + (size_t)s0 * NC))[t];
  float4 vb = ((const float4*)(Eo + (size_t)s1 * NC))[t];
  float4 o;
  o.x = va.x + vb.x; o.y = va.y + vb.y; o.z = va.z + vb.z; o.w = va.w + vb.w;
  ((float4*)(y + (size_t)n * NC))[t] = o;
}

extern "C" void kernel_launch(void* const* d_in, const int* in_sizes, int n_in,
                              void* d_out, int out_size, void* d_ws, size_t ws_size,
                              hipStream_t stream) {
  const float* x  = (const float*)d_in[0];
  const float* Wg = (const float*)d_in[1];
  const float* W1 = (const float*)d_in[2];
  const float* W2 = (const float*)d_in[3];
  float* y = (float*)d_out;

  char* p = (char*)d_ws;
  auto carve = [&](size_t bytes) {
    char* r = p;
    p += (bytes + 255) & ~(size_t)255;
    return r;
  };
  unsigned short* xbf  = (unsigned short*)carve((size_t)NN * NC * 2);     // 8.4 MB
  unsigned short* w1t  = (unsigned short*)carve((size_t)NE * NH * NC * 2); // 33.6 MB [E][H][C]
  unsigned short* w2t  = (unsigned short*)carve((size_t)NE * NC * NH * 2); // 33.6 MB [E][C][H]
  unsigned short* hbuf = (unsigned short*)carve((size_t)NSLOT * NH * 2);   // 33.6 MB
  float* eo = (float*)w1t;  // alias: W1t dead after gemm1; Eo written in gemm2 (same 33.6 MB)
  int*   tk_idx     = (int*)carve(NSLOT * 4);
  float* tk_p       = (float*)carve(NSLOT * 4);
  int*   slot_token = (int*)carve(NSLOT * 4);
  float* slot_w     = (float*)carve(NSLOT * 4);
  int*   slot_of    = (int*)carve(NSLOT * 4);
  int*   offs       = (int*)carve((NE + 1) * 4);

  // weight transpose + f32->bf16 (64x64 tiles, coalesced both sides)
  tcvt64_kernel<<<dim3(NH / 64, NC / 64, NE), 256, 0, stream>>>(W1, w1t, NC, NH);
  tcvt64_kernel<<<dim3(NC / 64, NH / 64, NE), 256, 0, stream>>>(W2, w2t, NH, NC);

  // routing (atomic-free) + fused x bf16 conversion
  router_kernel<<<dim3(NN / 4), 256, 0, stream>>>(x, Wg, xbf, tk_idx, tk_p);
  route_scan_scatter<<<1, 1024, 0, stream>>>(tk_idx, tk_p, offs,
                                             slot_token, slot_w, slot_of);

  // expert GEMMs (grouped, early-exit tiles beyond each expert's row count)
  moe_gemm_kernel<1, 1><<<dim3(NH / 128, NN / 128, NE), 256, 0, stream>>>(
      xbf, w1t, hbuf, slot_token, slot_w, offs, NC, NH);
  moe_gemm_kernel<0, 0><<<dim3(NC / 128, NN / 128, NE), 256, 0, stream>>>(
      hbuf, w2t, eo, slot_token, slot_w, offs, NH, NC);

  // weighted combine of each token's 2 expert rows
  combine_kernel<<<dim3(NN), 256, 0, stream>>>(eo, slot_of, y);
}